// Round 5
// baseline (123.097 us; speedup 1.0000x reference)
//
#include <hip/hip_runtime.h>

// Butterfly: out = butterfly_mult_untied(twiddle, x) + bias
// x: (32768, 1024) f32; twiddle: (1, 10, 512, 2, 2) f32; bias: (1024,) f32
// Stage idx pairs n with n^(1<<idx); p_idx(n) = n with bit idx deleted;
// out_idx(n) = sum_j t[idx][p][bit_idx(n)][j] * v(n with bit idx <- j).
//
// Layout: 512 threads/block, thread owns n = tid*2 + e (e=0,1).
//   stage 0: intra-thread (bit 0)
//   stage 1: lane^1  -> DPP quad_perm [1,0,3,2]           (VALU)
//   stage 2: lane^2  -> DPP quad_perm [2,3,0,1]           (VALU)
//   stage 3: lane^4  -> DPP row_shl:4 / row_shr:4 + sel   (VALU)
//            row_shr:N = dst lane gets src lane-N (data moves to higher lanes);
//            row_shl:N = dst lane gets src lane+N.  b4 set -> need src p-4 -> shr.
//   stage 4: lane^8  -> DPP row_ror:8 (rot by 8 mod 16 == xor 8)
//   stage 5: lane^16 -> v_permlane16_swap + cndmask       (VALU)
//   stage 6: lane^32 -> v_permlane32_swap + cndmask       (VALU)
//   stages 7+8+9: merged 8-term combo via one LDS roundtrip + barrier
//                 (partners tid ^ j*64, coeffs = product of 3 twiddles).

#define RPB 16        // rows per block
#define RB  4         // rows per batch (4 independent chains for ILP)
#define NB  (RPB/RB)  // batches per block

typedef int v2i __attribute__((ext_vector_type(2)));

template<int CTRL>
__device__ __forceinline__ float dppf(float v) {
    const int i = __float_as_int(v);
    return __int_as_float(__builtin_amdgcn_update_dpp(i, i, CTRL, 0xF, 0xF, true));
}

// lane^4 within a row-of-16: lanes with bit2=0 need src p+4 (row_shl:4),
// lanes with bit2=1 need src p-4 (row_shr:4).  [R4 bug: this select was inverted]
__device__ __forceinline__ float xor4f(float v, bool b4) {
    const float shl = dppf<0x104>(v);  // dst p = src p+4
    const float shr = dppf<0x114>(v);  // dst p = src p-4
    return b4 ? shr : shl;
}

__device__ __forceinline__ float xor16f(float v, bool hi16) {
#if __has_builtin(__builtin_amdgcn_permlane16_swap)
    const int i = __float_as_int(v);
    const v2i p = __builtin_amdgcn_permlane16_swap(i, i, false, false);
    return __int_as_float(hi16 ? p[0] : p[1]);
#else
    return __int_as_float(__builtin_amdgcn_ds_swizzle(__float_as_int(v), 0x401F));
#endif
}

__device__ __forceinline__ float xor32f(float v, bool hi32, int bpaddr) {
#if __has_builtin(__builtin_amdgcn_permlane32_swap)
    const int i = __float_as_int(v);
    const v2i p = __builtin_amdgcn_permlane32_swap(i, i, false, false);
    return __int_as_float(hi32 ? p[0] : p[1]);
#else
    return __int_as_float(__builtin_amdgcn_ds_bpermute(bpaddr, __float_as_int(v)));
#endif
}

__global__ __launch_bounds__(512, 4)
void butterfly_kernel(const float* __restrict__ x,
                      const float* __restrict__ tw,
                      const float* __restrict__ bias,
                      float* __restrict__ out) {
    __shared__ float2 lds[2][RB][512];
    const int tid  = threadIdx.x;
    const int lane = tid & 63;
    const bool b4set = (lane & 4)  != 0;
    const bool hi16  = (lane & 16) != 0;
    const bool hi32  = (lane & 32) != 0;
    const int bpaddr = ((lane ^ 32) & 63) << 2;
    const int n0 = tid * 2;
    const int w3 = tid >> 6;          // n bits 7..9 (b7,b8,b9) packed
    const int rowbase = blockIdx.x * RPB;

    // Issue batch-0 loads first: latency overlaps the twiddle preload.
    float2 cur[RB];
#pragma unroll
    for (int r = 0; r < RB; ++r)
        cur[r] = *reinterpret_cast<const float2*>(x + (size_t)(rowbase + r) * 1024 + n0);

    // ---- Twiddle preload (once per block) ----
    // Stages 0..6: (self, partner) coefficient per element.
    float twm[7][2], two_[7][2];
#pragma unroll
    for (int idx = 0; idx < 7; ++idx) {
        const int stride = 1 << idx;
#pragma unroll
        for (int e = 0; e < 2; ++e) {
            const int n = n0 + e;
            const int p = ((n >> (idx + 1)) << idx) | (n & (stride - 1));
            const int i = (n >> idx) & 1;
            const float* tp = tw + idx * 2048 + p * 4 + i * 2;  // &t[idx][p][i][0]
            twm[idx][e]  = tp[i];
            two_[idx][e] = tp[1 - i];
        }
    }
    // Stages 7+8+9 merged: out(n) = sum_j D[e][j] * w(value of thread tid^(j<<6)).
    // D indexed by XOR-distance j (static index in the hot loop -> stays in VGPRs).
    float D[2][8];
    {
        const int b7 = w3 & 1, b8 = (w3 >> 1) & 1, b9 = (w3 >> 2) & 1;
#pragma unroll
        for (int e = 0; e < 2; ++e) {
            const int n = n0 + e;
#pragma unroll
            for (int j = 0; j < 8; ++j) {
                const int k  = w3 ^ j;                  // absolute bits 7..9 of source
                const int j7 = k & 1, j8 = (k >> 1) & 1, j9 = (k >> 2) & 1;
                const float t9 = tw[9 * 2048 + (n & 511) * 4 + b9 * 2 + j9];
                const float t8 = tw[8 * 2048 + (((j9 << 8) | (n & 255))) * 4 + b8 * 2 + j8];
                const float t7 = tw[7 * 2048 + (((((j9 << 1) | j8) << 7) | (n & 127))) * 4 + b7 * 2 + j7];
                D[e][j] = t9 * t8 * t7;
            }
        }
    }
    float2 b2 = *reinterpret_cast<const float2*>(bias + n0);

    // Pin per-block constants (46 floats) so they stay VGPR-resident.
#pragma unroll
    for (int idx = 0; idx < 7; ++idx)
#pragma unroll
        for (int e = 0; e < 2; ++e)
            asm volatile("" : "+v"(twm[idx][e]), "+v"(two_[idx][e]));
#pragma unroll
    for (int e = 0; e < 2; ++e)
#pragma unroll
        for (int j = 0; j < 8; ++j)
            asm volatile("" : "+v"(D[e][j]));
    asm volatile("" : "+v"(b2.x), "+v"(b2.y));

    for (int b = 0; b < NB; ++b) {
        float v[RB][2];
#pragma unroll
        for (int r = 0; r < RB; ++r) { v[r][0] = cur[r].x; v[r][1] = cur[r].y; }

        // stage 0: intra-thread pair (e0,e1)
#pragma unroll
        for (int r = 0; r < RB; ++r) {
            const float a0 = twm[0][0] * v[r][0] + two_[0][0] * v[r][1];
            const float a1 = twm[0][1] * v[r][1] + two_[0][1] * v[r][0];
            v[r][0] = a0; v[r][1] = a1;
        }
        // stage 1: lane^1 (quad_perm [1,0,3,2] = 0xB1)
#pragma unroll
        for (int r = 0; r < RB; ++r)
#pragma unroll
            for (int e = 0; e < 2; ++e) {
                const float o = dppf<0xB1>(v[r][e]);
                v[r][e] = twm[1][e] * v[r][e] + two_[1][e] * o;
            }
        // stage 2: lane^2 (quad_perm [2,3,0,1] = 0x4E)
#pragma unroll
        for (int r = 0; r < RB; ++r)
#pragma unroll
            for (int e = 0; e < 2; ++e) {
                const float o = dppf<0x4E>(v[r][e]);
                v[r][e] = twm[2][e] * v[r][e] + two_[2][e] * o;
            }
        // stage 3: lane^4 (two DPP shifts + select, fixed direction)
#pragma unroll
        for (int r = 0; r < RB; ++r)
#pragma unroll
            for (int e = 0; e < 2; ++e) {
                const float o = xor4f(v[r][e], b4set);
                v[r][e] = twm[3][e] * v[r][e] + two_[3][e] * o;
            }
        // stage 4: lane^8 (row_ror:8 = 0x128)
#pragma unroll
        for (int r = 0; r < RB; ++r)
#pragma unroll
            for (int e = 0; e < 2; ++e) {
                const float o = dppf<0x128>(v[r][e]);
                v[r][e] = twm[4][e] * v[r][e] + two_[4][e] * o;
            }
        // stage 5: lane^16 (permlane16_swap)
#pragma unroll
        for (int r = 0; r < RB; ++r)
#pragma unroll
            for (int e = 0; e < 2; ++e) {
                const float o = xor16f(v[r][e], hi16);
                v[r][e] = twm[5][e] * v[r][e] + two_[5][e] * o;
            }
        // stage 6: lane^32 (permlane32_swap)
#pragma unroll
        for (int r = 0; r < RB; ++r)
#pragma unroll
            for (int e = 0; e < 2; ++e) {
                const float o = xor32f(v[r][e], hi32, bpaddr);
                v[r][e] = twm[6][e] * v[r][e] + two_[6][e] * o;
            }

        // merged stages 7+8+9: one LDS roundtrip, one barrier per batch (4 rows).
        const int buf = b & 1;
#pragma unroll
        for (int r = 0; r < RB; ++r)
            lds[buf][r][tid] = make_float2(v[r][0], v[r][1]);
        __syncthreads();

        // Prefetch next batch: no barrier between issue and use.
        if (b + 1 < NB) {
#pragma unroll
            for (int r = 0; r < RB; ++r)
                cur[r] = *reinterpret_cast<const float2*>(
                    x + (size_t)(rowbase + (b + 1) * RB + r) * 1024 + n0);
        }

#pragma unroll
        for (int r = 0; r < RB; ++r) {
            float s0 = D[0][0] * v[r][0] + b2.x;   // self term (j=0) from register
            float s1 = D[1][0] * v[r][1] + b2.y;
#pragma unroll
            for (int j = 1; j < 8; ++j) {
                const float2 o = lds[buf][r][tid ^ (j << 6)];
                s0 += D[0][j] * o.x;
                s1 += D[1][j] * o.y;
            }
            float2 sv; sv.x = s0; sv.y = s1;
            *reinterpret_cast<float2*>(out + (size_t)(rowbase + b * RB + r) * 1024 + n0) = sv;
        }
        // Double buffer + one barrier/batch: a thread's next write to this buf
        // happens only after all threads passed the NEXT barrier, which follows
        // every thread's reads of this buf. Race-free.
    }
}

extern "C" void kernel_launch(void* const* d_in, const int* in_sizes, int n_in,
                              void* d_out, int out_size, void* d_ws, size_t ws_size,
                              hipStream_t stream) {
    const float* x    = (const float*)d_in[0];
    const float* tw   = (const float*)d_in[1];
    const float* bias = (const float*)d_in[2];
    float* outp = (float*)d_out;
    dim3 grid(32768 / RPB);   // 2048 blocks
    dim3 block(512);
    hipLaunchKernelGGL(butterfly_kernel, grid, block, 0, stream, x, tw, bias, outp);
}

// Round 6
// 83.210 us; speedup vs baseline: 1.4794x; 1.4794x over previous
//
#include <hip/hip_runtime.h>

// Butterfly: out = butterfly_mult_untied(twiddle, x) + bias
// x: (32768, 1024) f32; twiddle: (1, 10, 512, 2, 2) f32; bias: (1024,) f32
// Stage idx pairs n with n^(1<<idx); p_idx(n) = n with bit idx deleted;
// out(n) = t[p][i][i]*v(n) + t[p][i][1-i]*v(n^stride), i = bit idx of n.
//
// Layout (R3-proven): 256 threads, thread owns n = tid*4 + e (e=0..3).
//   stages 0-1: intra-thread (bits 0-1)
//   stage 2: lane^1  -> DPP quad_perm [1,0,3,2]          (VALU)
//   stage 3: lane^2  -> DPP quad_perm [2,3,0,1]          (VALU)
//   stage 4: lane^4  -> DPP row_shl:4/row_shr:4 + sel    (VALU, R5-validated)
//   stage 5: lane^8  -> DPP row_ror:8                    (VALU)
//   stage 6: lane^16 -> v_permlane16_swap + cndmask      (VALU)
//   stage 7: lane^32 -> v_permlane32_swap + cndmask      (VALU)
//   stages 8-9: merged 4-term combo via one LDS roundtrip + barrier.
// R6: launch_bounds(256,3) so pinned twiddles live in real VGPRs (not AGPRs);
//     RB=4 rows/batch -> 16 independent chains/wave; 4 barriers/block.

#define RPB 16        // rows per block
#define RB  4         // rows per batch
#define NB  (RPB/RB)  // batches per block

typedef int v2i __attribute__((ext_vector_type(2)));

template<int CTRL>
__device__ __forceinline__ float dppf(float v) {
    const int i = __float_as_int(v);
    return __int_as_float(__builtin_amdgcn_update_dpp(i, i, CTRL, 0xF, 0xF, true));
}

// lane^4 within a row-of-16: bit2=0 -> src p+4 (row_shl:4); bit2=1 -> src p-4
// (row_shr:4). Validated in R5.
__device__ __forceinline__ float xor4f(float v, bool b4) {
    const float shl = dppf<0x104>(v);
    const float shr = dppf<0x114>(v);
    return b4 ? shr : shl;
}

__device__ __forceinline__ float xor16f(float v, bool hi16) {
#if __has_builtin(__builtin_amdgcn_permlane16_swap)
    const int i = __float_as_int(v);
    const v2i p = __builtin_amdgcn_permlane16_swap(i, i, false, false);
    return __int_as_float(hi16 ? p[0] : p[1]);
#else
    return __int_as_float(__builtin_amdgcn_ds_swizzle(__float_as_int(v), 0x401F));
#endif
}

__device__ __forceinline__ float xor32f(float v, bool hi32, int bpaddr) {
#if __has_builtin(__builtin_amdgcn_permlane32_swap)
    const int i = __float_as_int(v);
    const v2i p = __builtin_amdgcn_permlane32_swap(i, i, false, false);
    return __int_as_float(hi32 ? p[0] : p[1]);
#else
    return __int_as_float(__builtin_amdgcn_ds_bpermute(bpaddr, __float_as_int(v)));
#endif
}

__global__ __launch_bounds__(256, 3)
void butterfly_kernel(const float* __restrict__ x,
                      const float* __restrict__ tw,
                      const float* __restrict__ bias,
                      float* __restrict__ out) {
    __shared__ float4 lds[2][RB][256];
    const int tid  = threadIdx.x;
    const int lane = tid & 63;
    const bool b4set = (lane & 4)  != 0;
    const bool hi16  = (lane & 16) != 0;
    const bool hi32  = (lane & 32) != 0;
    const int bpaddr = ((lane ^ 32) & 63) << 2;
    const int n0 = tid * 4;
    const int rowbase = blockIdx.x * RPB;

    // Batch-0 loads first: latency overlaps the twiddle preload.
    float4 cur[RB];
#pragma unroll
    for (int r = 0; r < RB; ++r)
        cur[r] = *reinterpret_cast<const float4*>(x + (size_t)(rowbase + r) * 1024 + n0);

    // ---- Twiddle preload (once per block), pre-swapped (self, partner) ----
    float twm[8][4], two_[8][4];
#pragma unroll
    for (int idx = 0; idx < 8; ++idx) {
        const int stride = 1 << idx;
#pragma unroll
        for (int e = 0; e < 4; ++e) {
            const int n = n0 + e;
            const int p = ((n >> (idx + 1)) << idx) | (n & (stride - 1));
            const int i = (n >> idx) & 1;
            const float* tp = tw + idx * 2048 + p * 4 + i * 2;
            twm[idx][e]  = tp[i];
            two_[idx][e] = tp[1 - i];
        }
    }
    // Stages 8+9 merged: out(n) = c0*w(n) + c1*w(n^256) + c2*w(n^512) + c3*w(n^768)
    float c0[4], c1[4], c2[4], c3[4];
    {
        const int b8 = (tid >> 6) & 1;
        const int b9 = (tid >> 7) & 1;
#pragma unroll
        for (int e = 0; e < 4; ++e) {
            const int n   = n0 + e;
            const int low = n & 255;
            const int p9  = n & 511;
            const float* t9p = tw + 9 * 2048 + p9 * 4 + b9 * 2;
            const float A = t9p[b9], B = t9p[1 - b9];
            const float* t8a = tw + 8 * 2048 + (( b9      << 8) | low) * 4 + b8 * 2;
            const float* t8b = tw + 8 * 2048 + (((1 - b9) << 8) | low) * 4 + b8 * 2;
            c0[e] = A * t8a[b8];
            c1[e] = A * t8a[1 - b8];
            c2[e] = B * t8b[b8];
            c3[e] = B * t8b[1 - b8];
        }
    }
    float4 b4v = *reinterpret_cast<const float4*>(bias + n0);

    // Pin per-block constants: forbid per-row rematerialization.
#pragma unroll
    for (int idx = 0; idx < 8; ++idx)
#pragma unroll
        for (int e = 0; e < 4; ++e)
            asm volatile("" : "+v"(twm[idx][e]), "+v"(two_[idx][e]));
#pragma unroll
    for (int e = 0; e < 4; ++e)
        asm volatile("" : "+v"(c0[e]), "+v"(c1[e]), "+v"(c2[e]), "+v"(c3[e]));
    asm volatile("" : "+v"(b4v.x), "+v"(b4v.y), "+v"(b4v.z), "+v"(b4v.w));

    for (int b = 0; b < NB; ++b) {
        float v[RB][4];
#pragma unroll
        for (int r = 0; r < RB; ++r) {
            v[r][0] = cur[r].x; v[r][1] = cur[r].y; v[r][2] = cur[r].z; v[r][3] = cur[r].w;
        }
        // stage 0 (stride 1): pairs (e0,e1),(e2,e3)
#pragma unroll
        for (int r = 0; r < RB; ++r) {
            float a0 = twm[0][0] * v[r][0] + two_[0][0] * v[r][1];
            float a1 = twm[0][1] * v[r][1] + two_[0][1] * v[r][0];
            float a2 = twm[0][2] * v[r][2] + two_[0][2] * v[r][3];
            float a3 = twm[0][3] * v[r][3] + two_[0][3] * v[r][2];
            v[r][0] = a0; v[r][1] = a1; v[r][2] = a2; v[r][3] = a3;
        }
        // stage 1 (stride 2): pairs (e0,e2),(e1,e3)
#pragma unroll
        for (int r = 0; r < RB; ++r) {
            float a0 = twm[1][0] * v[r][0] + two_[1][0] * v[r][2];
            float a1 = twm[1][1] * v[r][1] + two_[1][1] * v[r][3];
            float a2 = twm[1][2] * v[r][2] + two_[1][2] * v[r][0];
            float a3 = twm[1][3] * v[r][3] + two_[1][3] * v[r][1];
            v[r][0] = a0; v[r][1] = a1; v[r][2] = a2; v[r][3] = a3;
        }
        // stage 2: lane^1 (quad_perm [1,0,3,2])
#pragma unroll
        for (int r = 0; r < RB; ++r)
#pragma unroll
            for (int e = 0; e < 4; ++e) {
                const float o = dppf<0xB1>(v[r][e]);
                v[r][e] = twm[2][e] * v[r][e] + two_[2][e] * o;
            }
        // stage 3: lane^2 (quad_perm [2,3,0,1])
#pragma unroll
        for (int r = 0; r < RB; ++r)
#pragma unroll
            for (int e = 0; e < 4; ++e) {
                const float o = dppf<0x4E>(v[r][e]);
                v[r][e] = twm[3][e] * v[r][e] + two_[3][e] * o;
            }
        // stage 4: lane^4 (two DPP shifts + select)
#pragma unroll
        for (int r = 0; r < RB; ++r)
#pragma unroll
            for (int e = 0; e < 4; ++e) {
                const float o = xor4f(v[r][e], b4set);
                v[r][e] = twm[4][e] * v[r][e] + two_[4][e] * o;
            }
        // stage 5: lane^8 (row_ror:8)
#pragma unroll
        for (int r = 0; r < RB; ++r)
#pragma unroll
            for (int e = 0; e < 4; ++e) {
                const float o = dppf<0x128>(v[r][e]);
                v[r][e] = twm[5][e] * v[r][e] + two_[5][e] * o;
            }
        // stage 6: lane^16 (permlane16_swap)
#pragma unroll
        for (int r = 0; r < RB; ++r)
#pragma unroll
            for (int e = 0; e < 4; ++e) {
                const float o = xor16f(v[r][e], hi16);
                v[r][e] = twm[6][e] * v[r][e] + two_[6][e] * o;
            }
        // stage 7: lane^32 (permlane32_swap)
#pragma unroll
        for (int r = 0; r < RB; ++r)
#pragma unroll
            for (int e = 0; e < 4; ++e) {
                const float o = xor32f(v[r][e], hi32, bpaddr);
                v[r][e] = twm[7][e] * v[r][e] + two_[7][e] * o;
            }
        // merged stages 8+9: one LDS roundtrip, one barrier per batch (4 rows).
        const int buf = b & 1;
#pragma unroll
        for (int r = 0; r < RB; ++r)
            lds[buf][r][tid] = make_float4(v[r][0], v[r][1], v[r][2], v[r][3]);
        __syncthreads();

        // Prefetch next batch: stays in flight (no barrier between issue and use).
        if (b + 1 < NB) {
#pragma unroll
            for (int r = 0; r < RB; ++r)
                cur[r] = *reinterpret_cast<const float4*>(
                    x + (size_t)(rowbase + (b + 1) * RB + r) * 1024 + n0);
        }

#pragma unroll
        for (int r = 0; r < RB; ++r) {
            const float4 o64  = lds[buf][r][tid ^ 64];
            const float4 o128 = lds[buf][r][tid ^ 128];
            const float4 o192 = lds[buf][r][tid ^ 192];
            float4 s;
            s.x = c0[0]*v[r][0] + c1[0]*o64.x + c2[0]*o128.x + c3[0]*o192.x + b4v.x;
            s.y = c0[1]*v[r][1] + c1[1]*o64.y + c2[1]*o128.y + c3[1]*o192.y + b4v.y;
            s.z = c0[2]*v[r][2] + c1[2]*o64.z + c2[2]*o128.z + c3[2]*o192.z + b4v.z;
            s.w = c0[3]*v[r][3] + c1[3]*o64.w + c2[3]*o128.w + c3[3]*o192.w + b4v.w;
            *reinterpret_cast<float4*>(out + (size_t)(rowbase + b * RB + r) * 1024 + n0) = s;
        }
        // Race-free per the double-buffer + one-barrier argument (R3/R5-proven).
    }
}

extern "C" void kernel_launch(void* const* d_in, const int* in_sizes, int n_in,
                              void* d_out, int out_size, void* d_ws, size_t ws_size,
                              hipStream_t stream) {
    const float* x    = (const float*)d_in[0];
    const float* tw   = (const float*)d_in[1];
    const float* bias = (const float*)d_in[2];
    float* outp = (float*)d_out;
    dim3 grid(32768 / RPB);   // 2048 blocks
    dim3 block(256);
    hipLaunchKernelGGL(butterfly_kernel, grid, block, 0, stream, x, tw, bias, outp);
}

// Round 7
// 83.152 us; speedup vs baseline: 1.4804x; 1.0007x over previous
//
#include <hip/hip_runtime.h>
#include <hip/hip_fp16.h>

// Butterfly: out = butterfly_mult_untied(twiddle, x) + bias
// x: (32768, 1024) f32; twiddle: (1, 10, 512, 2, 2) f32; bias: (1024,) f32
// Stage idx pairs n with n^(1<<idx); p_idx(n) = n with bit idx deleted;
// out(n) = t[p][i][i]*v(n) + t[p][i][1-i]*v(n^stride), i = bit idx of n.
//
// Layout (R3/R6-proven): 256 threads, thread owns n = tid*4 + e (e=0..3).
//   stages 0-1: intra-thread; stages 2-7: DPP/permlane (VALU only);
//   stages 8-9: merged 4-term combo via one LDS roundtrip + barrier.
// R7: coefficients packed as __half2 (lo=self, hi=partner) -> 40 coeff VGPRs
//     instead of 84 f32. Kills the R6 AGPR shadow (76 VGPR + ~96 AGPR = 172
//     unified regs -> 2.3 waves/SIMD) that made the kernel latency-bound.
//     fp16 coeff rounding: <=9 applications x 2^-11 rel on |out|<=25 -> ~0.1
//     abs error, threshold 0.5125.

#define RPB 16        // rows per block
#define RB  4         // rows per batch
#define NB  (RPB/RB)  // batches per block

typedef int v2i __attribute__((ext_vector_type(2)));

template<int CTRL>
__device__ __forceinline__ float dppf(float v) {
    const int i = __float_as_int(v);
    return __int_as_float(__builtin_amdgcn_update_dpp(i, i, CTRL, 0xF, 0xF, true));
}

// lane^4 within a row-of-16: bit2=0 -> src p+4 (row_shl:4); bit2=1 -> src p-4
// (row_shr:4). Validated R5/R6.
__device__ __forceinline__ float xor4f(float v, bool b4) {
    const float shl = dppf<0x104>(v);
    const float shr = dppf<0x114>(v);
    return b4 ? shr : shl;
}

__device__ __forceinline__ float xor16f(float v, bool hi16) {
#if __has_builtin(__builtin_amdgcn_permlane16_swap)
    const int i = __float_as_int(v);
    const v2i p = __builtin_amdgcn_permlane16_swap(i, i, false, false);
    return __int_as_float(hi16 ? p[0] : p[1]);
#else
    return __int_as_float(__builtin_amdgcn_ds_swizzle(__float_as_int(v), 0x401F));
#endif
}

__device__ __forceinline__ float xor32f(float v, bool hi32, int bpaddr) {
#if __has_builtin(__builtin_amdgcn_permlane32_swap)
    const int i = __float_as_int(v);
    const v2i p = __builtin_amdgcn_permlane32_swap(i, i, false, false);
    return __int_as_float(hi32 ? p[0] : p[1]);
#else
    return __int_as_float(__builtin_amdgcn_ds_bpermute(bpaddr, __float_as_int(v)));
#endif
}

__device__ __forceinline__ float flo(__half2 h) { return __half2float(__low2half(h)); }
__device__ __forceinline__ float fhi(__half2 h) { return __half2float(__high2half(h)); }

__global__ __launch_bounds__(256, 4)
void butterfly_kernel(const float* __restrict__ x,
                      const float* __restrict__ tw,
                      const float* __restrict__ bias,
                      float* __restrict__ out) {
    __shared__ float4 lds[2][RB][256];
    const int tid  = threadIdx.x;
    const int lane = tid & 63;
    const bool b4set = (lane & 4)  != 0;
    const bool hi16  = (lane & 16) != 0;
    const bool hi32  = (lane & 32) != 0;
    const int bpaddr = ((lane ^ 32) & 63) << 2;
    const int n0 = tid * 4;
    const int rowbase = blockIdx.x * RPB;

    // Batch-0 loads first: latency overlaps the twiddle preload.
    float4 cur[RB];
#pragma unroll
    for (int r = 0; r < RB; ++r)
        cur[r] = *reinterpret_cast<const float4*>(x + (size_t)(rowbase + r) * 1024 + n0);

    // ---- Twiddle preload (once per block) ----
    // Stages 0..7: packed __half2, lo = self coeff, hi = partner coeff.
    __half2 hc[8][4];
#pragma unroll
    for (int idx = 0; idx < 8; ++idx) {
        const int stride = 1 << idx;
#pragma unroll
        for (int e = 0; e < 4; ++e) {
            const int n = n0 + e;
            const int p = ((n >> (idx + 1)) << idx) | (n & (stride - 1));
            const int i = (n >> idx) & 1;
            const float* tp = tw + idx * 2048 + p * 4 + i * 2;
            hc[idx][e] = __halves2half2(__float2half(tp[i]), __float2half(tp[1 - i]));
        }
    }
    // Stages 8+9 merged: out(n) = c0*w(n) + c1*w(n^256) + c2*w(n^512) + c3*w(n^768)
    // packed as hd01 = (c0,c1), hd23 = (c2,c3); products formed in f32, then rounded.
    __half2 hd01[4], hd23[4];
    {
        const int b8 = (tid >> 6) & 1;
        const int b9 = (tid >> 7) & 1;
#pragma unroll
        for (int e = 0; e < 4; ++e) {
            const int n   = n0 + e;
            const int low = n & 255;
            const int p9  = n & 511;
            const float* t9p = tw + 9 * 2048 + p9 * 4 + b9 * 2;
            const float A = t9p[b9], B = t9p[1 - b9];
            const float* t8a = tw + 8 * 2048 + (( b9      << 8) | low) * 4 + b8 * 2;
            const float* t8b = tw + 8 * 2048 + (((1 - b9) << 8) | low) * 4 + b8 * 2;
            hd01[e] = __halves2half2(__float2half(A * t8a[b8]), __float2half(A * t8a[1 - b8]));
            hd23[e] = __halves2half2(__float2half(B * t8b[b8]), __float2half(B * t8b[1 - b8]));
        }
    }
    float4 b4v = *reinterpret_cast<const float4*>(bias + n0);

    // Pin the (small) coefficient set: forbids per-row rematerialization without
    // blowing the register budget (40 x __half2 + 4 f32 bias).
#pragma unroll
    for (int idx = 0; idx < 8; ++idx)
#pragma unroll
        for (int e = 0; e < 4; ++e)
            asm volatile("" : "+v"(hc[idx][e]));
#pragma unroll
    for (int e = 0; e < 4; ++e)
        asm volatile("" : "+v"(hd01[e]), "+v"(hd23[e]));
    asm volatile("" : "+v"(b4v.x), "+v"(b4v.y), "+v"(b4v.z), "+v"(b4v.w));

    for (int b = 0; b < NB; ++b) {
        float v[RB][4];
#pragma unroll
        for (int r = 0; r < RB; ++r) {
            v[r][0] = cur[r].x; v[r][1] = cur[r].y; v[r][2] = cur[r].z; v[r][3] = cur[r].w;
        }
        // stage 0 (stride 1): pairs (e0,e1),(e2,e3)
#pragma unroll
        for (int r = 0; r < RB; ++r) {
            float a0 = flo(hc[0][0]) * v[r][0] + fhi(hc[0][0]) * v[r][1];
            float a1 = flo(hc[0][1]) * v[r][1] + fhi(hc[0][1]) * v[r][0];
            float a2 = flo(hc[0][2]) * v[r][2] + fhi(hc[0][2]) * v[r][3];
            float a3 = flo(hc[0][3]) * v[r][3] + fhi(hc[0][3]) * v[r][2];
            v[r][0] = a0; v[r][1] = a1; v[r][2] = a2; v[r][3] = a3;
        }
        // stage 1 (stride 2): pairs (e0,e2),(e1,e3)
#pragma unroll
        for (int r = 0; r < RB; ++r) {
            float a0 = flo(hc[1][0]) * v[r][0] + fhi(hc[1][0]) * v[r][2];
            float a1 = flo(hc[1][1]) * v[r][1] + fhi(hc[1][1]) * v[r][3];
            float a2 = flo(hc[1][2]) * v[r][2] + fhi(hc[1][2]) * v[r][0];
            float a3 = flo(hc[1][3]) * v[r][3] + fhi(hc[1][3]) * v[r][1];
            v[r][0] = a0; v[r][1] = a1; v[r][2] = a2; v[r][3] = a3;
        }
        // stage 2: lane^1 (quad_perm [1,0,3,2])
#pragma unroll
        for (int r = 0; r < RB; ++r)
#pragma unroll
            for (int e = 0; e < 4; ++e) {
                const float o = dppf<0xB1>(v[r][e]);
                v[r][e] = flo(hc[2][e]) * v[r][e] + fhi(hc[2][e]) * o;
            }
        // stage 3: lane^2 (quad_perm [2,3,0,1])
#pragma unroll
        for (int r = 0; r < RB; ++r)
#pragma unroll
            for (int e = 0; e < 4; ++e) {
                const float o = dppf<0x4E>(v[r][e]);
                v[r][e] = flo(hc[3][e]) * v[r][e] + fhi(hc[3][e]) * o;
            }
        // stage 4: lane^4 (two DPP shifts + select)
#pragma unroll
        for (int r = 0; r < RB; ++r)
#pragma unroll
            for (int e = 0; e < 4; ++e) {
                const float o = xor4f(v[r][e], b4set);
                v[r][e] = flo(hc[4][e]) * v[r][e] + fhi(hc[4][e]) * o;
            }
        // stage 5: lane^8 (row_ror:8)
#pragma unroll
        for (int r = 0; r < RB; ++r)
#pragma unroll
            for (int e = 0; e < 4; ++e) {
                const float o = dppf<0x128>(v[r][e]);
                v[r][e] = flo(hc[5][e]) * v[r][e] + fhi(hc[5][e]) * o;
            }
        // stage 6: lane^16 (permlane16_swap)
#pragma unroll
        for (int r = 0; r < RB; ++r)
#pragma unroll
            for (int e = 0; e < 4; ++e) {
                const float o = xor16f(v[r][e], hi16);
                v[r][e] = flo(hc[6][e]) * v[r][e] + fhi(hc[6][e]) * o;
            }
        // stage 7: lane^32 (permlane32_swap)
#pragma unroll
        for (int r = 0; r < RB; ++r)
#pragma unroll
            for (int e = 0; e < 4; ++e) {
                const float o = xor32f(v[r][e], hi32, bpaddr);
                v[r][e] = flo(hc[7][e]) * v[r][e] + fhi(hc[7][e]) * o;
            }
        // merged stages 8+9: one LDS roundtrip, one barrier per batch (4 rows).
        const int buf = b & 1;
#pragma unroll
        for (int r = 0; r < RB; ++r)
            lds[buf][r][tid] = make_float4(v[r][0], v[r][1], v[r][2], v[r][3]);
        __syncthreads();

        // Prefetch next batch: stays in flight (no barrier between issue and use).
        if (b + 1 < NB) {
#pragma unroll
            for (int r = 0; r < RB; ++r)
                cur[r] = *reinterpret_cast<const float4*>(
                    x + (size_t)(rowbase + (b + 1) * RB + r) * 1024 + n0);
        }

#pragma unroll
        for (int r = 0; r < RB; ++r) {
            const float4 o64  = lds[buf][r][tid ^ 64];
            const float4 o128 = lds[buf][r][tid ^ 128];
            const float4 o192 = lds[buf][r][tid ^ 192];
            float4 s;
            s.x = flo(hd01[0])*v[r][0] + fhi(hd01[0])*o64.x + flo(hd23[0])*o128.x + fhi(hd23[0])*o192.x + b4v.x;
            s.y = flo(hd01[1])*v[r][1] + fhi(hd01[1])*o64.y + flo(hd23[1])*o128.y + fhi(hd23[1])*o192.y + b4v.y;
            s.z = flo(hd01[2])*v[r][2] + fhi(hd01[2])*o64.z + flo(hd23[2])*o128.z + fhi(hd23[2])*o192.z + b4v.z;
            s.w = flo(hd01[3])*v[r][3] + fhi(hd01[3])*o64.w + flo(hd23[3])*o128.w + fhi(hd23[3])*o192.w + b4v.w;
            *reinterpret_cast<float4*>(out + (size_t)(rowbase + b * RB + r) * 1024 + n0) = s;
        }
        // Race-free per the double-buffer + one-barrier argument (R3/R5/R6-proven).
    }
}

extern "C" void kernel_launch(void* const* d_in, const int* in_sizes, int n_in,
                              void* d_out, int out_size, void* d_ws, size_t ws_size,
                              hipStream_t stream) {
    const float* x    = (const float*)d_in[0];
    const float* tw   = (const float*)d_in[1];
    const float* bias = (const float*)d_in[2];
    float* outp = (float*)d_out;
    dim3 grid(32768 / RPB);   // 2048 blocks
    dim3 block(256);
    hipLaunchKernelGGL(butterfly_kernel, grid, block, 0, stream, x, tw, bias, outp);
}